// Round 4
// baseline (265.008 us; speedup 1.0000x reference)
//
#include <hip/hip_runtime.h>
#include <hip/hip_bf16.h>
#include <hip/hip_fp16.h>

// Problem constants (fixed by setup_inputs)
#define NROWS 4096
#define IDIM  512
#define HDIM  2048
#define ODIM  512
#define NG    8      // groups (prefix structure)
#define NCH   8      // H chunks
#define HC    256    // H per chunk
#define TM    64     // rows per main block

typedef __attribute__((ext_vector_type(8))) short short8;   // 8 bf16
typedef __attribute__((ext_vector_type(4))) float f32x4;

__device__ __forceinline__ unsigned short f2bf(float f) {
    unsigned int u = __float_as_uint(f);
    unsigned int r = (u + 0x7fffu + ((u >> 16) & 1u)) >> 16;
    return (unsigned short)r;
}

// async global->LDS, 16B per lane; lds base must be wave-uniform (HW adds lane*16)
__device__ __forceinline__ void glds16(const unsigned short* g, unsigned short* l) {
    __builtin_amdgcn_global_load_lds(
        (const __attribute__((address_space(1))) unsigned int*)g,
        (__attribute__((address_space(3))) unsigned int*)l, 16, 0, 0);
}

// ---- Prep kernel: x-convert + W1/W2 transpose-convert + counter zero ----
// grid 1537: [0,1024) x; [1024,1536) W transpose; 1536 zeroes row-group
// arrival counters (workspace is poisoned per iteration).
__global__ __launch_bounds__(256) void k_prep(const float* __restrict__ x,
                                              const float* __restrict__ W1,
                                              const float* __restrict__ W2,
                                              unsigned short* __restrict__ xb,
                                              unsigned short* __restrict__ w1t,
                                              unsigned short* __restrict__ w2t,
                                              int* __restrict__ cnt) {
    __shared__ float tile[64 * 68];
    const int bz = blockIdx.x;
    const int t = threadIdx.x;
    if (bz < 1024) {
        int gt = bz * 256 + t;                    // x: 262144 threads, 8 floats each
        const float4* src = reinterpret_cast<const float4*>(x) + (size_t)gt * 2;
        float4 a = src[0], b = src[1];
        unsigned short o[8] = { f2bf(a.x), f2bf(a.y), f2bf(a.z), f2bf(a.w),
                                f2bf(b.x), f2bf(b.y), f2bf(b.z), f2bf(b.w) };
        *reinterpret_cast<uint4*>(xb + (size_t)gt * 8) = *reinterpret_cast<uint4*>(o);
        return;
    }
    if (bz >= 1536) {                             // zero arrival counters
        if (t < NROWS / TM) cnt[t] = 0;
        return;
    }
    int b = bz - 1024;
    const float* in;
    unsigned short* outp;
    int R, C, c0, r0;
    if (b < 256) {            // W1: 512x2048 -> w1t[2048][512]
        in = W1; outp = w1t; R = 512; C = 2048;
        c0 = (b & 31) * 64; r0 = (b >> 5) * 64;
    } else {                  // W2: 2048x512 -> w2t[512][2048]
        b -= 256;
        in = W2; outp = w2t; R = 2048; C = 512;
        c0 = (b & 7) * 64; r0 = (b >> 3) * 64;
    }
    const int tx = t & 15, ty = t >> 4;
    #pragma unroll
    for (int p = 0; p < 4; ++p) {
        int rr = p * 16 + ty;
        float4 v = *reinterpret_cast<const float4*>(&in[(size_t)(r0 + rr) * C + c0 + tx * 4]);
        tile[rr * 68 + tx * 4 + 0] = v.x;
        tile[rr * 68 + tx * 4 + 1] = v.y;
        tile[rr * 68 + tx * 4 + 2] = v.z;
        tile[rr * 68 + tx * 4 + 3] = v.w;
    }
    __syncthreads();
    #pragma unroll
    for (int p = 0; p < 4; ++p) {
        int rr = p * 16 + ty;
        int cc = tx * 4;
        ushort4 o;
        o.x = f2bf(tile[(cc + 0) * 68 + rr]);
        o.y = f2bf(tile[(cc + 1) * 68 + rr]);
        o.z = f2bf(tile[(cc + 2) * 68 + rr]);
        o.w = f2bf(tile[(cc + 3) * 68 + rr]);
        *reinterpret_cast<ushort4*>(&outp[(size_t)(c0 + rr) * R + r0 + cc]) = o;
    }
}

// ---- Kernel 1: fused prefix-GEMM1^T + relu + GEMM2 partials + tail-reduce ----
// grid (8, 64) = 512 blocks (2/CU), 512 threads (8 waves). LDS 72KB.
// Body identical to the proven R1 kernel (fp16 P partials, counted-vmcnt,
// half2 P-stores). NEW: after the g-loop, each block drains its P stores,
// agent-release fences (__threadfence -> L2 writeback, cross-XCD visible),
// and bumps cnt[row-group]. The 8th arrival acquire-fences and reduces its
// 64x512 slice (sum 8 chunks + b2 -> out). 512 atomics total; reduction
// overlaps the remaining chunk-blocks; k_reduce dispatch eliminated.
__global__ __launch_bounds__(512, 4) void k_main(const unsigned short* __restrict__ xb,   // [4096][512]
                                                 const unsigned short* __restrict__ w1t,  // [2048][512] = W1^T
                                                 const unsigned short* __restrict__ w2t,  // [512][2048] = W2^T
                                                 const float* __restrict__ b1,            // [2048]
                                                 const float* __restrict__ b2,            // [512]
                                                 __half* __restrict__ P,                  // [NCH][4096][512] fp16
                                                 int* __restrict__ cnt,                   // [64]
                                                 float* __restrict__ out) {               // [4096][512]
    __shared__ unsigned short sX[64 * 64];        // x_g  [sample][k]  8KB  (swizzled ^row&7)
    __shared__ unsigned short sW[64 * 256];       // W2_g [j][k]      32KB  (swizzled ^(row>>1)&7)
    __shared__ unsigned short sH[64 * 256];       // h    [sample][h] 32KB  (swizzled ^row&7)

    const int chunk = blockIdx.x;                 // 0..7
    const int row0  = blockIdx.y * TM;
    const int hbase = chunk * HC;

    const int t    = threadIdx.x;
    const int lane = t & 63, wv = t >> 6;         // wave 0..7
    const int l16  = lane & 15, quad = lane >> 4;

    // bias for this lane's h rows: h_local = wv*32 + ct*16 + quad*4 + r
    f32x4 acc1[2][4];
    #pragma unroll
    for (int ct = 0; ct < 2; ++ct) {
        f32x4 bv;
        #pragma unroll
        for (int r = 0; r < 4; ++r)
            bv[r] = b1[hbase + wv * 32 + ct * 16 + quad * 4 + r];
        #pragma unroll
        for (int rt = 0; rt < 4; ++rt) acc1[ct][rt] = bv;
    }

    const int srow = t >> 3;                      // sX staging row (0..63)
    const int scb  = t & 7;                       // sX staging 16B-block
    const int rt2  = wv >> 1;                     // GEMM2 row-tile
    const int jb   = (wv & 1) * 32;               // GEMM2 col base
    __half* Pc = P + (size_t)chunk * (NROWS * ODIM);
    const unsigned short* w1p = w1t + (size_t)(hbase + wv * 32 + l16) * 512 + quad * 8;

    for (int g = 0; g < NG; ++g) {
        // B0: prev GEMM2 LDS reads done (lgkm only; P-stores stay in flight)
        asm volatile("s_waitcnt lgkmcnt(0)" ::: "memory");
        __builtin_amdgcn_s_barrier();
        __builtin_amdgcn_sched_barrier(0);

        // stage x_g (8KB), W1 frags (regs), W2_g (32KB) — in this issue order
        glds16(xb + (size_t)(row0 + srow) * 512 + g * 64 + ((scb ^ (srow & 7)) << 3),
               sX + (size_t)(t & ~63) * 8);
        short8 w1f[2][2];
        #pragma unroll
        for (int kst = 0; kst < 2; ++kst)
            #pragma unroll
            for (int ct = 0; ct < 2; ++ct)
                w1f[kst][ct] = *reinterpret_cast<const short8*>(
                    w1p + (size_t)ct * 16 * 512 + g * 64 + kst * 32);
        #pragma unroll
        for (int i = 0; i < 4; ++i) {
            int slot = i * 512 + t;               // 0..2047
            int jr = slot >> 5, cb = slot & 31;   // jr 0..63, cb 0..31
            glds16(w2t + (size_t)(g * 64 + jr) * 2048 + hbase + ((cb ^ ((jr >> 1) & 7)) << 3),
                   sW + (size_t)(slot & ~63) * 8);
        }
        // B1: ordinal vmcnt(4): prev P-stores + sX + w1f complete; the 4 sW
        // glds (newest) remain in flight and drain under GEMM1+sH-pack
        asm volatile("s_waitcnt vmcnt(4) lgkmcnt(0)" ::: "memory");
        __builtin_amdgcn_s_barrier();
        __builtin_amdgcn_sched_barrier(0);

        // ---- GEMM1^T: acc1 += W1_g(A) x x_g(B) -> D[h][sample] ----
        #pragma unroll
        for (int kst = 0; kst < 2; ++kst) {
            short8 xf[4];
            #pragma unroll
            for (int rt = 0; rt < 4; ++rt) {
                int row = rt * 16 + l16;
                xf[rt] = *reinterpret_cast<const short8*>(
                    &sX[row * 64 + (((kst * 4 + quad) ^ (row & 7)) << 3)]);
            }
            #pragma unroll
            for (int ct = 0; ct < 2; ++ct)
                #pragma unroll
                for (int rt = 0; rt < 4; ++rt)
                    acc1[ct][rt] = __builtin_amdgcn_mfma_f32_16x16x32_bf16(
                        w1f[kst][ct], xf[rt], acc1[ct][rt], 0, 0, 0);
        }

        // ---- h = relu(acc1) -> sH via v_cvt_pk_bf16_f32 (RNE) ----
        #pragma unroll
        for (int ct = 0; ct < 2; ++ct) {
            const int cb2 = wv * 4 + ct * 2 + (quad >> 1);  // 16B-block of h
            #pragma unroll
            for (int rt = 0; rt < 4; ++rt) {
                const int sample = rt * 16 + l16;
                float m0 = fmaxf(acc1[ct][rt][0], 0.f);
                float m1 = fmaxf(acc1[ct][rt][1], 0.f);
                float m2 = fmaxf(acc1[ct][rt][2], 0.f);
                float m3 = fmaxf(acc1[ct][rt][3], 0.f);
                unsigned int p0, p1;
                asm("v_cvt_pk_bf16_f32 %0, %1, %2" : "=v"(p0) : "v"(m0), "v"(m1));
                asm("v_cvt_pk_bf16_f32 %0, %1, %2" : "=v"(p1) : "v"(m2), "v"(m3));
                uint2 pk = { p0, p1 };
                *reinterpret_cast<uint2*>(
                    &sH[sample * 256 + ((cb2 ^ (sample & 7)) << 3) + (quad & 1) * 4]) = pk;
            }
        }
        // B2: sW glds drained + sH writes visible
        asm volatile("s_waitcnt vmcnt(0) lgkmcnt(0)" ::: "memory");
        __builtin_amdgcn_s_barrier();
        __builtin_amdgcn_sched_barrier(0);

        // ---- GEMM2: P_g = h @ W2_g  (K=256 -> 8 ksteps, 2 tiles/wave) ----
        // B rows mapped j = jb + 2*l16 + c so each lane's two j are adjacent.
        f32x4 acc2[2];
        acc2[0] = 0.f; acc2[1] = 0.f;
        #pragma unroll
        for (int kst = 0; kst < 8; ++kst) {
            int arow = rt2 * 16 + l16;
            const short8 a = *reinterpret_cast<const short8*>(
                &sH[arow * 256 + (((kst * 4 + quad) ^ (arow & 7)) << 3)]);
            #pragma unroll
            for (int c = 0; c < 2; ++c) {
                int brow = jb + 2 * l16 + c;
                const short8 b = *reinterpret_cast<const short8*>(
                    &sW[brow * 256 + (((kst * 4 + quad) ^ ((brow >> 1) & 7)) << 3)]);
                acc2[c] = __builtin_amdgcn_mfma_f32_16x16x32_bf16(a, b, acc2[c], 0, 0, 0);
            }
        }
        #pragma unroll
        for (int r = 0; r < 4; ++r) {
            __half2 pk;
            pk.x = __float2half(acc2[0][r]);
            pk.y = __float2half(acc2[1][r]);
            *reinterpret_cast<__half2*>(
                &Pc[(size_t)(row0 + rt2 * 16 + quad * 4 + r) * 512 +
                    g * 64 + jb + 2 * l16]) = pk;
        }
    }

    // ---- tail: publish P slice, last-arriving chunk-block reduces ----
    asm volatile("s_waitcnt vmcnt(0)" ::: "memory");  // all P stores issued+done
    __threadfence();                                  // agent release (L2 wb)
    __shared__ int sTicket;
    __syncthreads();                                  // all threads fenced
    if (t == 0) sTicket = atomicAdd(&cnt[blockIdx.y], 1);
    __syncthreads();
    if (sTicket == NCH - 1) {
        __threadfence();                              // acquire (invalidate)
        // reduce rows [row0, row0+64): thread = 8-col octet x 8 rows
        const int o8 = (t & 63) * 8;                  // col base
        const int rb = (t >> 6) * 8;                  // row base (8 rows)
        float b2v[8];
        *reinterpret_cast<float4*>(&b2v[0]) = *reinterpret_cast<const float4*>(&b2[o8]);
        *reinterpret_cast<float4*>(&b2v[4]) = *reinterpret_cast<const float4*>(&b2[o8 + 4]);
        for (int rr = 0; rr < 8; ++rr) {
            const size_t roff = (size_t)(row0 + rb + rr) * 512 + o8;
            float s[8];
            #pragma unroll
            for (int k = 0; k < 8; ++k) s[k] = b2v[k];
            #pragma unroll
            for (int c = 0; c < NCH; ++c) {
                uint4 v = *reinterpret_cast<const uint4*>(P + (size_t)c * (NROWS * ODIM) + roff);
                const __half2* hp = reinterpret_cast<const __half2*>(&v);
                #pragma unroll
                for (int k = 0; k < 4; ++k) {
                    float2 f = __half22float2(hp[k]);
                    s[2 * k + 0] += f.x;
                    s[2 * k + 1] += f.y;
                }
            }
            *reinterpret_cast<float4*>(&out[roff])     = *reinterpret_cast<float4*>(&s[0]);
            *reinterpret_cast<float4*>(&out[roff + 4]) = *reinterpret_cast<float4*>(&s[4]);
        }
    }
}

extern "C" void kernel_launch(void* const* d_in, const int* in_sizes, int n_in,
                              void* d_out, int out_size, void* d_ws, size_t ws_size,
                              hipStream_t stream) {
    const float* x  = (const float*)d_in[0];
    const float* W1 = (const float*)d_in[1];
    const float* b1 = (const float*)d_in[2];
    const float* W2 = (const float*)d_in[3];
    const float* b2 = (const float*)d_in[4];
    float* out = (float*)d_out;

    unsigned short* xb  = (unsigned short*)d_ws;                          // 4 MB
    unsigned short* w1t = (unsigned short*)((char*)d_ws + (4u << 20));    // 2 MB
    unsigned short* w2t = (unsigned short*)((char*)d_ws + (6u << 20));    // 2 MB
    __half*         P   = (__half*)((char*)d_ws + (8u << 20));            // 32 MB fp16
    int*            cnt = (int*)((char*)d_ws + (40u << 20));              // 256 B

    k_prep<<<1537, 256, 0, stream>>>(x, W1, W2, xb, w1t, w2t, cnt);
    k_main<<<dim3(NCH, NROWS / TM), 512, 0, stream>>>(xb, w1t, w2t, b1, b2, P, cnt, out);
}

// Round 5
// 146.186 us; speedup vs baseline: 1.8128x; 1.8128x over previous
//
#include <hip/hip_runtime.h>
#include <hip/hip_bf16.h>
#include <hip/hip_fp16.h>

// Problem constants (fixed by setup_inputs)
#define NROWS 4096
#define IDIM  512
#define HDIM  2048
#define ODIM  512
#define NG    8      // groups (prefix structure)
#define NCH   8      // H chunks
#define HC    256    // H per chunk
#define TM    64     // rows per main block

typedef __attribute__((ext_vector_type(8))) short short8;   // 8 bf16
typedef __attribute__((ext_vector_type(4))) float f32x4;

__device__ __forceinline__ unsigned short f2bf(float f) {
    unsigned int u = __float_as_uint(f);
    unsigned int r = (u + 0x7fffu + ((u >> 16) & 1u)) >> 16;
    return (unsigned short)r;
}

// async global->LDS, 16B per lane; lds base must be wave-uniform (HW adds lane*16)
__device__ __forceinline__ void glds16(const unsigned short* g, unsigned short* l) {
    __builtin_amdgcn_global_load_lds(
        (const __attribute__((address_space(1))) unsigned int*)g,
        (__attribute__((address_space(3))) unsigned int*)l, 16, 0, 0);
}

// ---- Prep kernel: fused x-convert + W1/W2 transpose-convert ----
// tile stride 65 floats: bank = (4*tx + ty + k) % 32 on both phases ->
// 2 lanes/bank (free), vs 8-way at stride 68.
__global__ __launch_bounds__(256) void k_prep(const float* __restrict__ x,
                                              const float* __restrict__ W1,
                                              const float* __restrict__ W2,
                                              unsigned short* __restrict__ xb,
                                              unsigned short* __restrict__ w1t,
                                              unsigned short* __restrict__ w2t) {
    __shared__ float tile[64 * 65];
    const int bz = blockIdx.x;
    const int t = threadIdx.x;
    if (bz < 1024) {
        int gt = bz * 256 + t;                    // x: 262144 threads, 8 floats each
        const float4* src = reinterpret_cast<const float4*>(x) + (size_t)gt * 2;
        float4 a = src[0], b = src[1];
        unsigned short o[8] = { f2bf(a.x), f2bf(a.y), f2bf(a.z), f2bf(a.w),
                                f2bf(b.x), f2bf(b.y), f2bf(b.z), f2bf(b.w) };
        *reinterpret_cast<uint4*>(xb + (size_t)gt * 8) = *reinterpret_cast<uint4*>(o);
        return;
    }
    int b = bz - 1024;
    const float* in;
    unsigned short* out;
    int R, C, c0, r0;
    if (b < 256) {            // W1: 512x2048 -> w1t[2048][512]
        in = W1; out = w1t; R = 512; C = 2048;
        c0 = (b & 31) * 64; r0 = (b >> 5) * 64;
    } else {                  // W2: 2048x512 -> w2t[512][2048]
        b -= 256;
        in = W2; out = w2t; R = 2048; C = 512;
        c0 = (b & 7) * 64; r0 = (b >> 3) * 64;
    }
    const int tx = t & 15, ty = t >> 4;
    #pragma unroll
    for (int p = 0; p < 4; ++p) {
        int rr = p * 16 + ty;
        float4 v = *reinterpret_cast<const float4*>(&in[(size_t)(r0 + rr) * C + c0 + tx * 4]);
        tile[rr * 65 + tx * 4 + 0] = v.x;
        tile[rr * 65 + tx * 4 + 1] = v.y;
        tile[rr * 65 + tx * 4 + 2] = v.z;
        tile[rr * 65 + tx * 4 + 3] = v.w;
    }
    __syncthreads();
    #pragma unroll
    for (int p = 0; p < 4; ++p) {
        int rr = p * 16 + ty;
        int cc = tx * 4;
        ushort4 o;
        o.x = f2bf(tile[(cc + 0) * 65 + rr]);
        o.y = f2bf(tile[(cc + 1) * 65 + rr]);
        o.z = f2bf(tile[(cc + 2) * 65 + rr]);
        o.w = f2bf(tile[(cc + 3) * 65 + rr]);
        *reinterpret_cast<ushort4*>(&out[(size_t)(c0 + rr) * R + r0 + cc]) = o;
    }
}

// ---- Kernel 1: fused prefix-GEMM1^T + relu + GEMM2 partials (fp16) ----
// grid (8, 64) = 512 blocks (2/CU), 512 threads (8 waves). LDS 64KB (no sX).
// GEMM1 consumes ONLY registers: both W1 fragments (w1f) and x fragments
// (xf) load global->VGPR; x block-slice (64KB) is L2-resident across its
// 8-g reuse. This removes 64 ds_read_b128/block-g AND the pre-GEMM1
// barrier: per g only B0 (prev GEMM2 reads done) and B2 (sH+sW ready).
// Counted-vmcnt: issue {xf(8), w1f(4)} then [sched_barrier] {sW glds(4)};
// vmcnt(4) before GEMM1 -> xf+w1f (and older P-stores) complete, the 4 sW
// glds stay in flight and drain under GEMM1+sH-pack; B2 waits vmcnt(0).
__global__ __launch_bounds__(512, 4) void k_main(const unsigned short* __restrict__ xb,   // [4096][512]
                                                 const unsigned short* __restrict__ w1t,  // [2048][512] = W1^T
                                                 const unsigned short* __restrict__ w2t,  // [512][2048] = W2^T
                                                 const float* __restrict__ b1,            // [2048]
                                                 __half* __restrict__ P) {                // [NCH][4096][512] fp16
    __shared__ unsigned short sW[64 * 256];       // W2_g [j][k]      32KB  (swizzled ^(row>>1)&7)
    __shared__ unsigned short sH[64 * 256];       // h    [sample][h] 32KB  (swizzled ^row&7)

    const int chunk = blockIdx.x;                 // 0..7
    const int row0  = blockIdx.y * TM;
    const int hbase = chunk * HC;

    const int t    = threadIdx.x;
    const int lane = t & 63, wv = t >> 6;         // wave 0..7
    const int l16  = lane & 15, quad = lane >> 4;

    // bias for this lane's h rows: h_local = wv*32 + ct*16 + quad*4 + r
    // acc1 = S + b1 from the start (bias never re-added per g)
    f32x4 acc1[2][4];
    #pragma unroll
    for (int ct = 0; ct < 2; ++ct) {
        f32x4 bv;
        #pragma unroll
        for (int r = 0; r < 4; ++r)
            bv[r] = b1[hbase + wv * 32 + ct * 16 + quad * 4 + r];
        #pragma unroll
        for (int rt = 0; rt < 4; ++rt) acc1[ct][rt] = bv;
    }

    const int rt2  = wv >> 1;                     // GEMM2 row-tile
    const int jb   = (wv & 1) * 32;               // GEMM2 col base
    __half* Pc = P + (size_t)chunk * (NROWS * ODIM);
    const unsigned short* w1p = w1t + (size_t)(hbase + wv * 32 + l16) * 512 + quad * 8;
    // xf source: sample = row0 + rt*16 + l16, k = g*64 + kst*32 + quad*8
    const unsigned short* xp = xb + (size_t)(row0 + l16) * 512 + quad * 8;

    for (int g = 0; g < NG; ++g) {
        // B0: prev GEMM2 LDS reads done (lgkm only; P-stores stay in flight)
        asm volatile("s_waitcnt lgkmcnt(0)" ::: "memory");
        __builtin_amdgcn_s_barrier();
        __builtin_amdgcn_sched_barrier(0);

        // xf: 8 global->VGPR 16B loads (2 kst x 4 rt), L2-hot
        short8 xf[2][4];
        #pragma unroll
        for (int kst = 0; kst < 2; ++kst)
            #pragma unroll
            for (int rt = 0; rt < 4; ++rt)
                xf[kst][rt] = *reinterpret_cast<const short8*>(
                    xp + (size_t)rt * 16 * 512 + g * 64 + kst * 32);
        // w1f: 4 global->VGPR 16B loads (disjoint per wave)
        short8 w1f[2][2];
        #pragma unroll
        for (int kst = 0; kst < 2; ++kst)
            #pragma unroll
            for (int ct = 0; ct < 2; ++ct)
                w1f[kst][ct] = *reinterpret_cast<const short8*>(
                    w1p + (size_t)ct * 16 * 512 + g * 64 + kst * 32);
        // pin issue order: xf/w1f BEFORE the sW glds (vmcnt(4) coverage)
        __builtin_amdgcn_sched_barrier(0);
        #pragma unroll
        for (int i = 0; i < 4; ++i) {
            int slot = i * 512 + t;               // 0..2047
            int jr = slot >> 5, cb = slot & 31;   // jr 0..63, cb 0..31
            glds16(w2t + (size_t)(g * 64 + jr) * 2048 + hbase + ((cb ^ ((jr >> 1) & 7)) << 3),
                   sW + (size_t)(slot & ~63) * 8);
        }
        // ordinal vmcnt(4): prev P-stores + xf + w1f complete; the 4 sW
        // glds (newest) remain in flight and drain under GEMM1+sH-pack.
        // No barrier needed: GEMM1 is register-only from here.
        asm volatile("s_waitcnt vmcnt(4)" ::: "memory");
        __builtin_amdgcn_sched_barrier(0);

        // ---- GEMM1^T: acc1 += W1_g(A) x x_g(B) -> D[h][sample] ----
        #pragma unroll
        for (int kst = 0; kst < 2; ++kst)
            #pragma unroll
            for (int ct = 0; ct < 2; ++ct)
                #pragma unroll
                for (int rt = 0; rt < 4; ++rt)
                    acc1[ct][rt] = __builtin_amdgcn_mfma_f32_16x16x32_bf16(
                        w1f[kst][ct], xf[kst][rt], acc1[ct][rt], 0, 0, 0);

        // ---- h = relu(acc1) -> sH via v_cvt_pk_bf16_f32 (RNE) ----
        #pragma unroll
        for (int ct = 0; ct < 2; ++ct) {
            const int cb2 = wv * 4 + ct * 2 + (quad >> 1);  // 16B-block of h
            #pragma unroll
            for (int rt = 0; rt < 4; ++rt) {
                const int sample = rt * 16 + l16;
                float m0 = fmaxf(acc1[ct][rt][0], 0.f);
                float m1 = fmaxf(acc1[ct][rt][1], 0.f);
                float m2 = fmaxf(acc1[ct][rt][2], 0.f);
                float m3 = fmaxf(acc1[ct][rt][3], 0.f);
                unsigned int p0, p1;
                asm("v_cvt_pk_bf16_f32 %0, %1, %2" : "=v"(p0) : "v"(m0), "v"(m1));
                asm("v_cvt_pk_bf16_f32 %0, %1, %2" : "=v"(p1) : "v"(m2), "v"(m3));
                uint2 pk = { p0, p1 };
                *reinterpret_cast<uint2*>(
                    &sH[sample * 256 + ((cb2 ^ (sample & 7)) << 3) + (quad & 1) * 4]) = pk;
            }
        }
        // B2: sW glds drained + sH writes visible
        asm volatile("s_waitcnt vmcnt(0) lgkmcnt(0)" ::: "memory");
        __builtin_amdgcn_s_barrier();
        __builtin_amdgcn_sched_barrier(0);

        // ---- GEMM2: P_g = h @ W2_g  (K=256 -> 8 ksteps, 2 tiles/wave) ----
        // B rows mapped j = jb + 2*l16 + c so each lane's two j are adjacent.
        f32x4 acc2[2];
        acc2[0] = 0.f; acc2[1] = 0.f;
        #pragma unroll
        for (int kst = 0; kst < 8; ++kst) {
            int arow = rt2 * 16 + l16;
            const short8 a = *reinterpret_cast<const short8*>(
                &sH[arow * 256 + (((kst * 4 + quad) ^ (arow & 7)) << 3)]);
            #pragma unroll
            for (int c = 0; c < 2; ++c) {
                int brow = jb + 2 * l16 + c;
                const short8 b = *reinterpret_cast<const short8*>(
                    &sW[brow * 256 + (((kst * 4 + quad) ^ ((brow >> 1) & 7)) << 3)]);
                acc2[c] = __builtin_amdgcn_mfma_f32_16x16x32_bf16(a, b, acc2[c], 0, 0, 0);
            }
        }
        #pragma unroll
        for (int r = 0; r < 4; ++r) {
            __half2 pk;
            pk.x = __float2half(acc2[0][r]);
            pk.y = __float2half(acc2[1][r]);
            *reinterpret_cast<__half2*>(
                &Pc[(size_t)(row0 + rt2 * 16 + quad * 4 + r) * 512 +
                    g * 64 + jb + 2 * l16]) = pk;
        }
    }
}

// ---- Kernel 2: out = sum_c P[c] + b2 ----
__global__ __launch_bounds__(256) void k_reduce(const __half* __restrict__ P,
                                                const float* __restrict__ b2,
                                                float* __restrict__ out) {
    int t = blockIdx.x * 256 + threadIdx.x;       // 524288 threads, 4 outputs each
    size_t f = (size_t)t * 4;
    int j = (int)(f & 511);
    float4 s = *reinterpret_cast<const float4*>(&b2[j]);
    #pragma unroll
    for (int c = 0; c < NCH; ++c) {
        const __half2* p = reinterpret_cast<const __half2*>(P + (size_t)c * (NROWS * ODIM) + f);
        float2 a = __half22float2(p[0]);
        float2 b = __half22float2(p[1]);
        s.x += a.x; s.y += a.y; s.z += b.x; s.w += b.y;
    }
    *reinterpret_cast<float4*>(&out[f]) = s;
}

extern "C" void kernel_launch(void* const* d_in, const int* in_sizes, int n_in,
                              void* d_out, int out_size, void* d_ws, size_t ws_size,
                              hipStream_t stream) {
    const float* x  = (const float*)d_in[0];
    const float* W1 = (const float*)d_in[1];
    const float* b1 = (const float*)d_in[2];
    const float* W2 = (const float*)d_in[3];
    const float* b2 = (const float*)d_in[4];
    float* out = (float*)d_out;

    unsigned short* xb  = (unsigned short*)d_ws;                          // 4 MB
    unsigned short* w1t = (unsigned short*)((char*)d_ws + (4u << 20));    // 2 MB
    unsigned short* w2t = (unsigned short*)((char*)d_ws + (6u << 20));    // 2 MB
    __half*         P   = (__half*)((char*)d_ws + (8u << 20));            // 32 MB fp16

    k_prep<<<1536, 256, 0, stream>>>(x, W1, W2, xb, w1t, w2t);
    k_main<<<dim3(NCH, NROWS / TM), 512, 0, stream>>>(xb, w1t, w2t, b1, P);
    k_reduce<<<2048, 256, 0, stream>>>(P, b2, out);
}

// Round 6
// 117.255 us; speedup vs baseline: 2.2601x; 1.2467x over previous
//
#include <hip/hip_runtime.h>
#include <hip/hip_bf16.h>
#include <hip/hip_fp16.h>

// Problem constants (fixed by setup_inputs)
#define NROWS 4096
#define IDIM  512
#define HDIM  2048
#define ODIM  512
#define NG    8      // groups (prefix structure)
#define NCH   8      // H chunks
#define HC    256    // H per chunk
#define TM    64     // rows per main block

typedef __attribute__((ext_vector_type(8))) short short8;   // 8 bf16
typedef __attribute__((ext_vector_type(4))) float f32x4;

__device__ __forceinline__ unsigned short f2bf(float f) {
    unsigned int u = __float_as_uint(f);
    unsigned int r = (u + 0x7fffu + ((u >> 16) & 1u)) >> 16;
    return (unsigned short)r;
}

// async global->LDS, 16B per lane; lds base must be wave-uniform (HW adds lane*16)
__device__ __forceinline__ void glds16(const unsigned short* g, unsigned short* l) {
    __builtin_amdgcn_global_load_lds(
        (const __attribute__((address_space(1))) unsigned int*)g,
        (__attribute__((address_space(3))) unsigned int*)l, 16, 0, 0);
}

// ---- Prep kernel: fused x-convert + W1/W2 transpose-convert ----
// tile stride 65 floats: write bank = (ty+4tx+k)%32 (b128 floor), read bank
// = (4tx+ty+k)%32 -> 2 lanes/bank (free). Old stride 68 read was 8-way.
__global__ __launch_bounds__(256) void k_prep(const float* __restrict__ x,
                                              const float* __restrict__ W1,
                                              const float* __restrict__ W2,
                                              unsigned short* __restrict__ xb,
                                              unsigned short* __restrict__ w1t,
                                              unsigned short* __restrict__ w2t) {
    __shared__ float tile[64 * 65];
    const int bz = blockIdx.x;
    const int t = threadIdx.x;
    if (bz < 1024) {
        int gt = bz * 256 + t;                    // x: 262144 threads, 8 floats each
        const float4* src = reinterpret_cast<const float4*>(x) + (size_t)gt * 2;
        float4 a = src[0], b = src[1];
        unsigned short o[8] = { f2bf(a.x), f2bf(a.y), f2bf(a.z), f2bf(a.w),
                                f2bf(b.x), f2bf(b.y), f2bf(b.z), f2bf(b.w) };
        *reinterpret_cast<uint4*>(xb + (size_t)gt * 8) = *reinterpret_cast<uint4*>(o);
        return;
    }
    int b = bz - 1024;
    const float* in;
    unsigned short* out;
    int R, C, c0, r0;
    if (b < 256) {            // W1: 512x2048 -> w1t[2048][512]
        in = W1; out = w1t; R = 512; C = 2048;
        c0 = (b & 31) * 64; r0 = (b >> 5) * 64;
    } else {                  // W2: 2048x512 -> w2t[512][2048]
        b -= 256;
        in = W2; out = w2t; R = 2048; C = 512;
        c0 = (b & 7) * 64; r0 = (b >> 3) * 64;
    }
    const int tx = t & 15, ty = t >> 4;
    #pragma unroll
    for (int p = 0; p < 4; ++p) {
        int rr = p * 16 + ty;
        float4 v = *reinterpret_cast<const float4*>(&in[(size_t)(r0 + rr) * C + c0 + tx * 4]);
        tile[rr * 65 + tx * 4 + 0] = v.x;
        tile[rr * 65 + tx * 4 + 1] = v.y;
        tile[rr * 65 + tx * 4 + 2] = v.z;
        tile[rr * 65 + tx * 4 + 3] = v.w;
    }
    __syncthreads();
    #pragma unroll
    for (int p = 0; p < 4; ++p) {
        int rr = p * 16 + ty;
        int cc = tx * 4;
        ushort4 o;
        o.x = f2bf(tile[(cc + 0) * 65 + rr]);
        o.y = f2bf(tile[(cc + 1) * 65 + rr]);
        o.z = f2bf(tile[(cc + 2) * 65 + rr]);
        o.w = f2bf(tile[(cc + 3) * 65 + rr]);
        *reinterpret_cast<ushort4*>(&out[(size_t)(c0 + rr) * R + r0 + cc]) = o;
    }
}

// ---- Kernel 1: fused prefix-GEMM1^T + relu + GEMM2 partials (fp16) ----
// PROVEN R1 STRUCTURE (measured 120.0us total) — do not restructure: both
// attempts to cut staging (direct xf loads R5, 32x32 1-block R2) regressed
// k_main ~25us. LDS read patterns are all at the b128 bank floor (8
// words/bank); SQ_LDS_BANK_CONFLICT ~4.2M is that floor, not fixable.
// grid (8, 64) = 512 blocks (2/CU), 512 threads (8 waves). LDS 72KB.
__global__ __launch_bounds__(512, 4) void k_main(const unsigned short* __restrict__ xb,   // [4096][512]
                                                 const unsigned short* __restrict__ w1t,  // [2048][512] = W1^T
                                                 const unsigned short* __restrict__ w2t,  // [512][2048] = W2^T
                                                 const float* __restrict__ b1,            // [2048]
                                                 __half* __restrict__ P) {                // [NCH][4096][512] fp16
    __shared__ unsigned short sX[64 * 64];        // x_g  [sample][k]  8KB  (swizzled ^row&7)
    __shared__ unsigned short sW[64 * 256];       // W2_g [j][k]      32KB  (swizzled ^(row>>1)&7)
    __shared__ unsigned short sH[64 * 256];       // h    [sample][h] 32KB  (swizzled ^row&7)

    const int chunk = blockIdx.x;                 // 0..7
    const int row0  = blockIdx.y * TM;
    const int hbase = chunk * HC;

    const int t    = threadIdx.x;
    const int lane = t & 63, wv = t >> 6;         // wave 0..7
    const int l16  = lane & 15, quad = lane >> 4;

    // bias for this lane's h rows: h_local = wv*32 + ct*16 + quad*4 + r
    f32x4 acc1[2][4];
    #pragma unroll
    for (int ct = 0; ct < 2; ++ct) {
        f32x4 bv;
        #pragma unroll
        for (int r = 0; r < 4; ++r)
            bv[r] = b1[hbase + wv * 32 + ct * 16 + quad * 4 + r];
        #pragma unroll
        for (int rt = 0; rt < 4; ++rt) acc1[ct][rt] = bv;
    }

    const int srow = t >> 3;                      // sX staging row (0..63)
    const int scb  = t & 7;                       // sX staging 16B-block
    const int rt2  = wv >> 1;                     // GEMM2 row-tile
    const int jb   = (wv & 1) * 32;               // GEMM2 col base
    __half* Pc = P + (size_t)chunk * (NROWS * ODIM);
    const unsigned short* w1p = w1t + (size_t)(hbase + wv * 32 + l16) * 512 + quad * 8;

    for (int g = 0; g < NG; ++g) {
        // B0: prev GEMM2 LDS reads done (lgkm only; P-stores stay in flight)
        asm volatile("s_waitcnt lgkmcnt(0)" ::: "memory");
        __builtin_amdgcn_s_barrier();
        __builtin_amdgcn_sched_barrier(0);

        // stage x_g (8KB), W1 frags (regs), W2_g (32KB) — in this issue order
        glds16(xb + (size_t)(row0 + srow) * 512 + g * 64 + ((scb ^ (srow & 7)) << 3),
               sX + (size_t)(t & ~63) * 8);
        short8 w1f[2][2];
        #pragma unroll
        for (int kst = 0; kst < 2; ++kst)
            #pragma unroll
            for (int ct = 0; ct < 2; ++ct)
                w1f[kst][ct] = *reinterpret_cast<const short8*>(
                    w1p + (size_t)ct * 16 * 512 + g * 64 + kst * 32);
        #pragma unroll
        for (int i = 0; i < 4; ++i) {
            int slot = i * 512 + t;               // 0..2047
            int jr = slot >> 5, cb = slot & 31;   // jr 0..63, cb 0..31
            glds16(w2t + (size_t)(g * 64 + jr) * 2048 + hbase + ((cb ^ ((jr >> 1) & 7)) << 3),
                   sW + (size_t)(slot & ~63) * 8);
        }
        // B1: ordinal vmcnt(4): prev P-stores + sX + w1f complete; the 4 sW
        // glds (newest) remain in flight and drain under GEMM1+sH-pack
        asm volatile("s_waitcnt vmcnt(4) lgkmcnt(0)" ::: "memory");
        __builtin_amdgcn_s_barrier();
        __builtin_amdgcn_sched_barrier(0);

        // ---- GEMM1^T: acc1 += W1_g(A) x x_g(B) -> D[h][sample] ----
        #pragma unroll
        for (int kst = 0; kst < 2; ++kst) {
            short8 xf[4];
            #pragma unroll
            for (int rt = 0; rt < 4; ++rt) {
                int row = rt * 16 + l16;
                xf[rt] = *reinterpret_cast<const short8*>(
                    &sX[row * 64 + (((kst * 4 + quad) ^ (row & 7)) << 3)]);
            }
            #pragma unroll
            for (int ct = 0; ct < 2; ++ct)
                #pragma unroll
                for (int rt = 0; rt < 4; ++rt)
                    acc1[ct][rt] = __builtin_amdgcn_mfma_f32_16x16x32_bf16(
                        w1f[kst][ct], xf[rt], acc1[ct][rt], 0, 0, 0);
        }

        // ---- h = relu(acc1) -> sH via v_cvt_pk_bf16_f32 (RNE) ----
        #pragma unroll
        for (int ct = 0; ct < 2; ++ct) {
            const int cb2 = wv * 4 + ct * 2 + (quad >> 1);  // 16B-block of h
            #pragma unroll
            for (int rt = 0; rt < 4; ++rt) {
                const int sample = rt * 16 + l16;
                float m0 = fmaxf(acc1[ct][rt][0], 0.f);
                float m1 = fmaxf(acc1[ct][rt][1], 0.f);
                float m2 = fmaxf(acc1[ct][rt][2], 0.f);
                float m3 = fmaxf(acc1[ct][rt][3], 0.f);
                unsigned int p0, p1;
                asm("v_cvt_pk_bf16_f32 %0, %1, %2" : "=v"(p0) : "v"(m0), "v"(m1));
                asm("v_cvt_pk_bf16_f32 %0, %1, %2" : "=v"(p1) : "v"(m2), "v"(m3));
                uint2 pk = { p0, p1 };
                *reinterpret_cast<uint2*>(
                    &sH[sample * 256 + ((cb2 ^ (sample & 7)) << 3) + (quad & 1) * 4]) = pk;
            }
        }
        // B2: sW glds drained + sH writes visible
        asm volatile("s_waitcnt vmcnt(0) lgkmcnt(0)" ::: "memory");
        __builtin_amdgcn_s_barrier();
        __builtin_amdgcn_sched_barrier(0);

        // ---- GEMM2: P_g = h @ W2_g  (K=256 -> 8 ksteps, 2 tiles/wave) ----
        // B rows mapped j = jb + 2*l16 + c so each lane's two j are adjacent.
        f32x4 acc2[2];
        acc2[0] = 0.f; acc2[1] = 0.f;
        #pragma unroll
        for (int kst = 0; kst < 8; ++kst) {
            int arow = rt2 * 16 + l16;
            const short8 a = *reinterpret_cast<const short8*>(
                &sH[arow * 256 + (((kst * 4 + quad) ^ (arow & 7)) << 3)]);
            #pragma unroll
            for (int c = 0; c < 2; ++c) {
                int brow = jb + 2 * l16 + c;
                const short8 b = *reinterpret_cast<const short8*>(
                    &sW[brow * 256 + (((kst * 4 + quad) ^ ((brow >> 1) & 7)) << 3)]);
                acc2[c] = __builtin_amdgcn_mfma_f32_16x16x32_bf16(a, b, acc2[c], 0, 0, 0);
            }
        }
        #pragma unroll
        for (int r = 0; r < 4; ++r) {
            __half2 pk;
            pk.x = __float2half(acc2[0][r]);
            pk.y = __float2half(acc2[1][r]);
            *reinterpret_cast<__half2*>(
                &Pc[(size_t)(row0 + rt2 * 16 + quad * 4 + r) * 512 +
                    g * 64 + jb + 2 * l16]) = pk;
        }
    }
}

// ---- Kernel 2: out = sum_c P[c] + b2 ----
// 8 outputs/thread, one uint4 (16B) load per chunk per thread (G13: the
// old two 4B half2 loads were under-vectorized). Summation order unchanged
// (b2 init, chunks ascending) -> bit-identical output.
__global__ __launch_bounds__(256) void k_reduce(const __half* __restrict__ P,
                                                const float* __restrict__ b2,
                                                float* __restrict__ out) {
    int t = blockIdx.x * 256 + threadIdx.x;       // 262144 threads, 8 outputs each
    size_t f = (size_t)t * 8;
    int j = (int)(f & 511);
    float s[8];
    *reinterpret_cast<float4*>(&s[0]) = *reinterpret_cast<const float4*>(&b2[j]);
    *reinterpret_cast<float4*>(&s[4]) = *reinterpret_cast<const float4*>(&b2[j + 4]);
    #pragma unroll
    for (int c = 0; c < NCH; ++c) {
        uint4 v = *reinterpret_cast<const uint4*>(P + (size_t)c * (NROWS * ODIM) + f);
        const __half2* hp = reinterpret_cast<const __half2*>(&v);
        #pragma unroll
        for (int k = 0; k < 4; ++k) {
            float2 a = __half22float2(hp[k]);
            s[2 * k + 0] += a.x;
            s[2 * k + 1] += a.y;
        }
    }
    *reinterpret_cast<float4*>(&out[f])     = *reinterpret_cast<float4*>(&s[0]);
    *reinterpret_cast<float4*>(&out[f + 4]) = *reinterpret_cast<float4*>(&s[4]);
}

extern "C" void kernel_launch(void* const* d_in, const int* in_sizes, int n_in,
                              void* d_out, int out_size, void* d_ws, size_t ws_size,
                              hipStream_t stream) {
    const float* x  = (const float*)d_in[0];
    const float* W1 = (const float*)d_in[1];
    const float* b1 = (const float*)d_in[2];
    const float* W2 = (const float*)d_in[3];
    const float* b2 = (const float*)d_in[4];
    float* out = (float*)d_out;

    unsigned short* xb  = (unsigned short*)d_ws;                          // 4 MB
    unsigned short* w1t = (unsigned short*)((char*)d_ws + (4u << 20));    // 2 MB
    unsigned short* w2t = (unsigned short*)((char*)d_ws + (6u << 20));    // 2 MB
    __half*         P   = (__half*)((char*)d_ws + (8u << 20));            // 32 MB fp16

    k_prep<<<1536, 256, 0, stream>>>(x, W1, W2, xb, w1t, w2t);
    k_main<<<dim3(NCH, NROWS / TM), 512, 0, stream>>>(xb, w1t, w2t, b1, P);
    k_reduce<<<1024, 256, 0, stream>>>(P, b2, out);
}